// Round 14
// baseline (350.395 us; speedup 1.0000x reference)
//
#include <hip/hip_runtime.h>
#include <hip/hip_bf16.h>

typedef __attribute__((ext_vector_type(8))) short short8;
typedef __attribute__((ext_vector_type(4))) float f32x4;
using bf16 = __hip_bfloat16;

#define NEG_SLOPE 0.2f
#define LN_EPS 1e-5f

__device__ __forceinline__ unsigned short f2bfu(float v) {
    bf16 t = __float2bfloat16(v);
    unsigned short s;
    __builtin_memcpy(&s, &t, 2);
    return s;
}
__device__ __forceinline__ short f2bf(float v) {
    bf16 t = __float2bfloat16(v);
    short s;
    __builtin_memcpy(&s, &t, 2);
    return s;
}
__device__ __forceinline__ unsigned packbf(float a, float b) {
    return (unsigned)f2bfu(a) | ((unsigned)f2bfu(b) << 16);
}
__device__ __forceinline__ float bflo(unsigned u) { return __uint_as_float(u << 16); }
__device__ __forceinline__ float bfhi(unsigned u) { return __uint_as_float(u & 0xffff0000u); }
__device__ __forceinline__ float bf1(unsigned short u) { return __uint_as_float(((unsigned)u) << 16); }

// -- dtype detect (flag=1 if f32 inputs) + init bucket cursors ---------------
__global__ void detect_k(const void* __restrict__ x, int* flag,
                         int* bucketCur, int CAP) {
    int lane = threadIdx.x;
    for (int i = lane; i < 512; i += 64) bucketCur[i] = i * CAP;
    const unsigned short* u = (const unsigned short*)x;
    float m = 0.f;
    for (int i = lane; i < 8192; i += 64) {
        float v = fabsf(bf1(u[i]));
        if (!(v == v)) v = 1e30f;
        m = fmaxf(m, v);
    }
    for (int d = 1; d < 64; d <<= 1) m = fmaxf(m, __shfl_xor(m, d));
    if (lane == 0) flag[0] = (m > 1e4f) ? 1 : 0;
}

// ---- staging: [0,256) W transpose ; 256 smalls ; [257,281) va fold ----------
struct Ptr4 { const void* p[4]; };
struct Ptr14 { const void* p[14]; };
struct Ptr3 { const void* p[3]; };
struct Ptr6 { const void* p[6]; };
__global__ void stage_k(Ptr4 Ws, bf16* __restrict__ WT,
                        Ptr14 ptrs, bf16* __restrict__ sv,
                        Ptr3 Wv, Ptr6 av, bf16* __restrict__ vaT,
                        const int* __restrict__ flag) {
    int b = blockIdx.x;
    int f = flag[0];
    if (b < 256) {
        int gid = b * 256 + threadIdx.x;            // 4*16384
        int m = gid >> 14;
        int idx = gid & 16383;
        int i = idx >> 7, j = idx & 127;
        const void* W = Ws.p[m];
        float v = f ? ((const float*)W)[idx]
                    : __bfloat162float(((const bf16*)W)[idx]);
        WT[m * 16384 + j * 128 + i] = __float2bfloat16(v);
    } else if (b == 256) {
        for (int k = threadIdx.x; k < 14 * 128; k += 256) {
            int t = k >> 7, i = k & 127;
            int n = (t == 12) ? 32 : 128;
            if (i < n) {
                const void* s = ptrs.p[t];
                float v = f ? ((const float*)s)[i]
                            : __bfloat162float(((const bf16*)s)[i]);
                sv[k] = __float2bfloat16(v);
            }
        }
    } else {
        int gid = (b - 257) * 256 + threadIdx.x;    // 3*16*128
        int l = gid >> 11;
        if (l >= 3) return;
        int c = (gid >> 7) & 15, k = gid & 127;
        float acc = 0.f;
        if (c < 8) {
            int hd = c & 3;
            const void* W = Wv.p[l];
            const void* a = av.p[l * 2 + (c >> 2)];
            for (int j = 0; j < 32; ++j) {
                float wv = f ? ((const float*)W)[k * 128 + hd * 32 + j]
                             : __bfloat162float(((const bf16*)W)[k * 128 + hd * 32 + j]);
                float avv = f ? ((const float*)a)[hd * 32 + j]
                              : __bfloat162float(((const bf16*)a)[hd * 32 + j]);
                acc += wv * avv;
            }
        }
        vaT[gid] = __float2bfloat16(acc);
    }
}

// ============ bucketed CSR build, fixed capacity (no count/scan) =============
#define SCAT_EPB 2048
__global__ __launch_bounds__(256) void bscatter_k(const int* __restrict__ src,
                                                  const int* __restrict__ dst,
                                                  int* bucketCur,
                                                  int* __restrict__ ebuf,
                                                  int E, int NB, int CAP) {
    __shared__ int lcnt[512], lbase[512];
    int t = threadIdx.x;
    int e0 = blockIdx.x * SCAT_EPB;
    int cnt = E - e0;
    if (cnt > SCAT_EPB) cnt = SCAT_EPB;
    for (int i = t; i < NB; i += 256) lcnt[i] = 0;
    __syncthreads();
    for (int i = t; i < cnt; i += 256)
        atomicAdd(&lcnt[dst[e0 + i] >> 7], 1);
    __syncthreads();
    for (int i = t; i < NB; i += 256) {
        int c = lcnt[i];
        lbase[i] = c ? atomicAdd(&bucketCur[i], c) : 0;
        lcnt[i] = 0;
    }
    __syncthreads();
    for (int i = t; i < cnt; i += 256) {
        int d = dst[e0 + i];
        int b = d >> 7;
        int pos = lbase[b] + atomicAdd(&lcnt[b], 1);
        if (pos < (b + 1) * CAP)
            ebuf[pos] = ((d & 127) << 16) | src[e0 + i];
    }
}

__global__ __launch_bounds__(256) void build_k(const int* __restrict__ ebuf,
                                               const int* __restrict__ bucketCur,
                                               int* __restrict__ rowSE,
                                               int* __restrict__ colSrc,
                                               int N, int CAP) {
    int b = blockIdx.x, t = threadIdx.x;
    int base = b * CAP;
    int cnt = bucketCur[b] - base;
    if (cnt > CAP) cnt = CAP;
    __shared__ int nodeCnt[128], nodeCur[128], ws2[2];
    if (t < 128) nodeCnt[t] = 0;
    __syncthreads();
    for (int i = t; i < cnt; i += 256)
        atomicAdd(&nodeCnt[ebuf[base + i] >> 16], 1);
    __syncthreads();
    int v = 0, incl = 0;
    if (t < 128) {
        v = nodeCnt[t];
        incl = v;
        for (int d = 1; d < 64; d <<= 1) {
            int u = __shfl_up(incl, d);
            if ((t & 63) >= d) incl += u;
        }
        if ((t & 63) == 63) ws2[t >> 6] = incl;
    }
    __syncthreads();
    if (t < 128) {
        int excl = incl - v + ((t >= 64) ? ws2[0] : 0);
        int node = b * 128 + t;
        if (node < N) {
            rowSE[node * 2] = base + excl;
            rowSE[node * 2 + 1] = base + excl + v;
        }
        nodeCur[t] = excl;
    }
    __syncthreads();
    for (int i = t; i < cnt; i += 256) {
        int p = ebuf[base + i];
        int pos = base + atomicAdd(&nodeCur[p >> 16], 1);
        colSrc[pos] = (p & 0xffff) << 8;       // byte offset src*256
    }
    for (int i = cnt + t; i < CAP; i += 256)   // zero slack (safe prefetch)
        colSrc[base + i] = 0;
}

// ---- MFMA GEMM (layer 1 only), persistent B, grid-stride, dual-output ------
template <int DUAL>
__global__ __launch_bounds__(256) void gemm_k(const void* __restrict__ A,
                                              const bf16* __restrict__ WT,
                                              bf16* __restrict__ out0,
                                              bf16* __restrict__ out1,
                                              const bf16* __restrict__ bias1,
                                              const bf16* __restrict__ vaT,
                                              float* __restrict__ asN,
                                              float* __restrict__ adN,
                                              int N, const int* __restrict__ flag) {
    int wave = threadIdx.x >> 6, lane = threadIdx.x & 63;
    int lm = lane & 15, lk = lane >> 4;
    const short* Ws = (const short*)WT;
    const short* Vs = (const short*)vaT;
    bool f32m = flag && flag[0];

    short8 bw0[2][4], bw1[DUAL ? 2 : 1][DUAL ? 4 : 1];
#pragma unroll
    for (int ct = 0; ct < 2; ++ct) {
        int c = (wave * 2 + ct) * 16 + lm;
#pragma unroll
        for (int kk = 0; kk < 4; ++kk)
            bw0[ct][kk] = *(const short8*)(Ws + (size_t)c * 128 + kk * 32 + lk * 8);
    }
    if (DUAL) {
#pragma unroll
        for (int ct = 0; ct < 2; ++ct) {
            int c = (wave * 2 + ct) * 16 + lm;
#pragma unroll
            for (int kk = 0; kk < 4; ++kk)
                bw1[ct][kk] = *(const short8*)(Ws + 16384 + (size_t)c * 128 + kk * 32 + lk * 8);
        }
    }
    short8 va8[4];
    if (wave == 0) {
#pragma unroll
        for (int kk = 0; kk < 4; ++kk)
            va8[kk] = *(const short8*)(Vs + (size_t)lm * 128 + kk * 32 + lk * 8);
    }
    float bv[DUAL ? 2 : 1];
    if (DUAL) {
#pragma unroll
        for (int ct = 0; ct < 2; ++ct)
            bv[ct] = __bfloat162float(bias1[(wave * 2 + ct) * 16 + lm]);
    }

    int stride = gridDim.x * 32;
    for (int rowBase = blockIdx.x * 32; rowBase < N; rowBase += stride) {
        short8 af[2][4];
#pragma unroll
        for (int rt = 0; rt < 2; ++rt) {
            int r = rowBase + rt * 16 + lm;
            if (r >= N) r = N - 1;
            if (f32m) {
#pragma unroll
                for (int kk = 0; kk < 4; ++kk) {
                    const float* Af = (const float*)A + (size_t)r * 128 + kk * 32 + lk * 8;
                    float4 q0 = *(const float4*)(Af);
                    float4 q1 = *(const float4*)(Af + 4);
                    short8 v;
                    v[0] = f2bf(q0.x); v[1] = f2bf(q0.y); v[2] = f2bf(q0.z); v[3] = f2bf(q0.w);
                    v[4] = f2bf(q1.x); v[5] = f2bf(q1.y); v[6] = f2bf(q1.z); v[7] = f2bf(q1.w);
                    af[rt][kk] = v;
                }
            } else {
#pragma unroll
                for (int kk = 0; kk < 4; ++kk)
                    af[rt][kk] = *(const short8*)((const short*)A + (size_t)r * 128 + kk * 32 + lk * 8);
            }
        }

        f32x4 acc0[2][2];
        f32x4 acc1[DUAL ? 2 : 1][DUAL ? 2 : 1];
#pragma unroll
        for (int ct = 0; ct < 2; ++ct)
#pragma unroll
            for (int rt = 0; rt < 2; ++rt) acc0[ct][rt] = (f32x4){0.f, 0.f, 0.f, 0.f};
        if (DUAL) {
#pragma unroll
            for (int ct = 0; ct < 2; ++ct)
#pragma unroll
                for (int rt = 0; rt < 2; ++rt) acc1[ct][rt] = (f32x4){0.f, 0.f, 0.f, 0.f};
        }

#pragma unroll
        for (int rt = 0; rt < 2; ++rt) {
#pragma unroll
            for (int kk = 0; kk < 4; ++kk) {
                acc0[0][rt] = __builtin_amdgcn_mfma_f32_16x16x32_bf16(af[rt][kk], bw0[0][kk], acc0[0][rt], 0, 0, 0);
                acc0[1][rt] = __builtin_amdgcn_mfma_f32_16x16x32_bf16(af[rt][kk], bw0[1][kk], acc0[1][rt], 0, 0, 0);
                if (DUAL) {
                    acc1[0][rt] = __builtin_amdgcn_mfma_f32_16x16x32_bf16(af[rt][kk], bw1[0][kk], acc1[0][rt], 0, 0, 0);
                    acc1[1][rt] = __builtin_amdgcn_mfma_f32_16x16x32_bf16(af[rt][kk], bw1[1][kk], acc1[1][rt], 0, 0, 0);
                }
            }
        }

#pragma unroll
        for (int ct = 0; ct < 2; ++ct) {
            int c = (wave * 2 + ct) * 16 + lm;
#pragma unroll
            for (int rt = 0; rt < 2; ++rt) {
#pragma unroll
                for (int i = 0; i < 4; ++i) {
                    int r = rowBase + rt * 16 + lk * 4 + i;
                    if (r < N) out0[(size_t)r * 128 + c] = __float2bfloat16(acc0[ct][rt][i]);
                }
            }
        }
        if (DUAL) {
#pragma unroll
            for (int ct = 0; ct < 2; ++ct) {
                int c = (wave * 2 + ct) * 16 + lm;
#pragma unroll
                for (int rt = 0; rt < 2; ++rt) {
#pragma unroll
                    for (int i = 0; i < 4; ++i) {
                        int r = rowBase + rt * 16 + lk * 4 + i;
                        if (r < N) out1[(size_t)r * 128 + c] = __float2bfloat16(acc1[ct][rt][i] + bv[ct]);
                    }
                }
            }
        }

        if (wave == 0) {
            f32x4 accA[2];
#pragma unroll
            for (int rt = 0; rt < 2; ++rt) accA[rt] = (f32x4){0.f, 0.f, 0.f, 0.f};
#pragma unroll
            for (int rt = 0; rt < 2; ++rt)
#pragma unroll
                for (int kk = 0; kk < 4; ++kk)
                    accA[rt] = __builtin_amdgcn_mfma_f32_16x16x32_bf16(af[rt][kk], va8[kk], accA[rt], 0, 0, 0);
            if (lm < 8) {
                float* dst = (lm < 4) ? asN : adN;
                int hh = lm & 3;
#pragma unroll
                for (int rt = 0; rt < 2; ++rt)
#pragma unroll
                    for (int i = 0; i < 4; ++i) {
                        int r = rowBase + rt * 16 + lk * 4 + i;
                        if (r < N) dst[(size_t)r * 4 + hh] = accA[rt][i];
                    }
            }
        }
    }
}

// ------- FUSED agg + next-layer GEMM. Block = 16 nodes (4 waves x 4 nodes) --
// agg phase identical per node (4 groups x 16 lanes); z rows staged in LDS
// (row stride 136ch = 272B, 2-way-conflict-free); gemm phase: each wave does
// its 32-col strip of hOut[16 rows] = z @ W_next, wave0 adds vaT alpha.
// MODE 1: +bias,ELU,LN,+skip (skip read from hOut's own row). MODE 2: no skip.
// hOut may alias the skip buffer (block-local rows only); must NOT alias h.
template <int MODE>
__global__ __launch_bounds__(256) void aggemm_k(const bf16* __restrict__ h,
                                                const float* __restrict__ asN,
                                                const float* __restrict__ adN,
                                                const int* __restrict__ rowSE,
                                                const int* __restrict__ colSrc,
                                                const bf16* __restrict__ bvec,
                                                const bf16* __restrict__ g,
                                                const bf16* __restrict__ be,
                                                const bf16* __restrict__ WT,
                                                const bf16* __restrict__ vaT,
                                                bf16* hOut,
                                                float* __restrict__ asOut,
                                                float* __restrict__ adOut, int N) {
    __shared__ unsigned short zs[16 * 136];        // 16 rows x 136ch (pad 8)
    int wv = threadIdx.x >> 6, lane = threadIdx.x & 63;
    int grp = lane >> 4, t = lane & 15;
    int hd = t >> 2;
    int blockBase = blockIdx.x * 16;
    const char* hbase = (const char*)h + t * 16;
    const char* abase = (const char*)asN + hd * 4;

    for (int q = 0; q < 4; ++q) {
        int n = blockBase + wv * 4 + q;
        uint4 zpk = make_uint4(0, 0, 0, 0);
        if (n < N) {
            int2 se = ((const int2*)rowSE)[n];
            int st = se.x, en = se.y;
            if (en < st) en = st;

            uint4 hself = *(const uint4*)(hbase + (size_t)n * 256);
            float adn = adN[(size_t)n * 4 + hd];
            float asn_self = asN[(size_t)n * 4 + hd];

            float a[8];
#pragma unroll
            for (int k = 0; k < 8; ++k) a[k] = 0.f;
            float den = 0.f;

            int j = st + grp;
            int off = (j < en) ? colSrc[j] : 0;
            float av = *(const float*)(abase + (off >> 4));
            uint4 hq = *(const uint4*)(hbase + off);
            for (; j < en; j += 4) {
                int off2 = colSrc[j + 4];
                float av2 = *(const float*)(abase + (off2 >> 4));
                uint4 hq2 = *(const uint4*)(hbase + off2);
                float e = av + adn;
                float w = __expf(fmaxf(e, NEG_SLOPE * e));
                den += w;
                a[0] += w * bflo(hq.x); a[1] += w * bfhi(hq.x);
                a[2] += w * bflo(hq.y); a[3] += w * bfhi(hq.y);
                a[4] += w * bflo(hq.z); a[5] += w * bfhi(hq.z);
                a[6] += w * bflo(hq.w); a[7] += w * bfhi(hq.w);
                av = av2; hq = hq2;
            }

#pragma unroll
            for (int k = 0; k < 8; ++k) {
                a[k] += __shfl_xor(a[k], 16);
                a[k] += __shfl_xor(a[k], 32);
            }
            den += __shfl_xor(den, 16);
            den += __shfl_xor(den, 32);

            float es = asn_self + adn;
            float wsf = __expf(fmaxf(es, NEG_SLOPE * es));
            den += wsf;
            a[0] += wsf * bflo(hself.x); a[1] += wsf * bfhi(hself.x);
            a[2] += wsf * bflo(hself.y); a[3] += wsf * bfhi(hself.y);
            a[4] += wsf * bflo(hself.z); a[5] += wsf * bfhi(hself.z);
            a[6] += wsf * bflo(hself.w); a[7] += wsf * bfhi(hself.w);

            float inv = 1.f / (den + 1e-16f);
            float y[8];
#pragma unroll
            for (int k = 0; k < 8; ++k) y[k] = a[k] * inv;

            uint4 bp = *(const uint4*)((const unsigned short*)bvec + t * 8);
            y[0] += bflo(bp.x); y[1] += bfhi(bp.x);
            y[2] += bflo(bp.y); y[3] += bfhi(bp.y);
            y[4] += bflo(bp.z); y[5] += bfhi(bp.z);
            y[6] += bflo(bp.w); y[7] += bfhi(bp.w);
#pragma unroll
            for (int k = 0; k < 8; ++k) y[k] = y[k] > 0.f ? y[k] : (__expf(y[k]) - 1.f);
            float s = 0.f, qq = 0.f;
#pragma unroll
            for (int k = 0; k < 8; ++k) { s += y[k]; qq += y[k] * y[k]; }
            for (int d = 1; d < 16; d <<= 1) {
                s += __shfl_xor(s, d);
                qq += __shfl_xor(qq, d);
            }
            float mu = s * (1.f / 128.f);
            float var = qq * (1.f / 128.f) - mu * mu;
            var = fmaxf(var, 0.f);
            float rs = rsqrtf(var + LN_EPS);
            if (lane < 16) {
                uint4 gp = *(const uint4*)((const unsigned short*)g + t * 8);
                uint4 ep = *(const uint4*)((const unsigned short*)be + t * 8);
                float z[8];
                z[0] = (y[0] - mu) * rs * bflo(gp.x) + bflo(ep.x);
                z[1] = (y[1] - mu) * rs * bfhi(gp.x) + bfhi(ep.x);
                z[2] = (y[2] - mu) * rs * bflo(gp.y) + bflo(ep.y);
                z[3] = (y[3] - mu) * rs * bfhi(gp.y) + bfhi(ep.y);
                z[4] = (y[4] - mu) * rs * bflo(gp.z) + bflo(ep.z);
                z[5] = (y[5] - mu) * rs * bfhi(gp.z) + bfhi(ep.z);
                z[6] = (y[6] - mu) * rs * bflo(gp.w) + bflo(ep.w);
                z[7] = (y[7] - mu) * rs * bfhi(gp.w) + bfhi(ep.w);
                if (MODE == 1) {
                    uint4 sk = *(uint4*)((unsigned short*)hOut + (size_t)n * 128 + t * 8);
                    z[0] += bflo(sk.x); z[1] += bfhi(sk.x);
                    z[2] += bflo(sk.y); z[3] += bfhi(sk.y);
                    z[4] += bflo(sk.z); z[5] += bfhi(sk.z);
                    z[6] += bflo(sk.w); z[7] += bfhi(sk.w);
                }
                zpk.x = packbf(z[0], z[1]); zpk.y = packbf(z[2], z[3]);
                zpk.z = packbf(z[4], z[5]); zpk.w = packbf(z[6], z[7]);
            }
        }
        if (lane < 16)
            *(uint4*)((char*)zs + (wv * 4 + q) * 272 + t * 16) = zpk;
    }
    __syncthreads();

    // ---- gemm phase: hOut[16 rows] = z @ W_next ; alpha via vaT ----
    int lm = t, lk = grp;
    const short* Ws = (const short*)WT;
    short8 af[4];
#pragma unroll
    for (int kk = 0; kk < 4; ++kk)
        af[kk] = *(const short8*)((const char*)zs + lm * 272 + kk * 64 + lk * 16);

    short8 bw[2][4];
#pragma unroll
    for (int ct = 0; ct < 2; ++ct) {
        int c = (wv * 2 + ct) * 16 + lm;
#pragma unroll
        for (int kk = 0; kk < 4; ++kk)
            bw[ct][kk] = *(const short8*)(Ws + (size_t)c * 128 + kk * 32 + lk * 8);
    }

    f32x4 acc[2];
    acc[0] = (f32x4){0.f, 0.f, 0.f, 0.f};
    acc[1] = (f32x4){0.f, 0.f, 0.f, 0.f};
#pragma unroll
    for (int kk = 0; kk < 4; ++kk) {
        acc[0] = __builtin_amdgcn_mfma_f32_16x16x32_bf16(af[kk], bw[0][kk], acc[0], 0, 0, 0);
        acc[1] = __builtin_amdgcn_mfma_f32_16x16x32_bf16(af[kk], bw[1][kk], acc[1], 0, 0, 0);
    }
#pragma unroll
    for (int ct = 0; ct < 2; ++ct) {
        int c = (wv * 2 + ct) * 16 + lm;
#pragma unroll
        for (int i = 0; i < 4; ++i) {
            int r = blockBase + lk * 4 + i;
            if (r < N) hOut[(size_t)r * 128 + c] = __float2bfloat16(acc[ct][i]);
        }
    }

    if (wv == 0) {
        const short* Vs = (const short*)vaT;
        short8 va8[4];
#pragma unroll
        for (int kk = 0; kk < 4; ++kk)
            va8[kk] = *(const short8*)(Vs + (size_t)lm * 128 + kk * 32 + lk * 8);
        f32x4 accA = (f32x4){0.f, 0.f, 0.f, 0.f};
#pragma unroll
        for (int kk = 0; kk < 4; ++kk)
            accA = __builtin_amdgcn_mfma_f32_16x16x32_bf16(af[kk], va8[kk], accA, 0, 0, 0);
        if (lm < 8) {
            float* dst = (lm < 4) ? asOut : adOut;
            int hh = lm & 3;
#pragma unroll
            for (int i = 0; i < 4; ++i) {
                int r = blockBase + lk * 4 + i;
                if (r < N) dst[(size_t)r * 4 + hh] = accA[i];
            }
        }
    }
}

// ------------- final-layer aggregation (MODE 3): head-mean -> d_out ---------
__global__ __launch_bounds__(256) void agg3_k(const bf16* __restrict__ h,
                                              const float* __restrict__ asN,
                                              const float* __restrict__ adN,
                                              const int* __restrict__ rowSE,
                                              const int* __restrict__ colSrc,
                                              const bf16* __restrict__ bvec,
                                              void* outv, int N,
                                              const int* __restrict__ flag) {
    int wv = threadIdx.x >> 6, lane = threadIdx.x & 63;
    int n = blockIdx.x * 4 + wv;
    if (n >= N) return;
    int grp = lane >> 4, t = lane & 15;
    int hd = t >> 2;
    const char* hbase = (const char*)h + t * 16;
    const char* abase = (const char*)asN + hd * 4;

    int2 se = ((const int2*)rowSE)[n];
    int st = se.x, en = se.y;
    if (en < st) en = st;

    uint4 hself = *(const uint4*)(hbase + (size_t)n * 256);
    float adn = adN[(size_t)n * 4 + hd];
    float asn_self = asN[(size_t)n * 4 + hd];

    float a[8];
#pragma unroll
    for (int k = 0; k < 8; ++k) a[k] = 0.f;
    float den = 0.f;

    int j = st + grp;
    int off = (j < en) ? colSrc[j] : 0;
    float av = *(const float*)(abase + (off >> 4));
    uint4 hq = *(const uint4*)(hbase + off);
    for (; j < en; j += 4) {
        int off2 = colSrc[j + 4];
        float av2 = *(const float*)(abase + (off2 >> 4));
        uint4 hq2 = *(const uint4*)(hbase + off2);
        float e = av + adn;
        float w = __expf(fmaxf(e, NEG_SLOPE * e));
        den += w;
        a[0] += w * bflo(hq.x); a[1] += w * bfhi(hq.x);
        a[2] += w * bflo(hq.y); a[3] += w * bfhi(hq.y);
        a[4] += w * bflo(hq.z); a[5] += w * bfhi(hq.z);
        a[6] += w * bflo(hq.w); a[7] += w * bfhi(hq.w);
        av = av2; hq = hq2;
    }

#pragma unroll
    for (int k = 0; k < 8; ++k) {
        a[k] += __shfl_xor(a[k], 16);
        a[k] += __shfl_xor(a[k], 32);
    }
    den += __shfl_xor(den, 16);
    den += __shfl_xor(den, 32);

    float es = asn_self + adn;
    float wsf = __expf(fmaxf(es, NEG_SLOPE * es));
    den += wsf;
    a[0] += wsf * bflo(hself.x); a[1] += wsf * bfhi(hself.x);
    a[2] += wsf * bflo(hself.y); a[3] += wsf * bfhi(hself.y);
    a[4] += wsf * bflo(hself.z); a[5] += wsf * bfhi(hself.z);
    a[6] += wsf * bflo(hself.w); a[7] += wsf * bfhi(hself.w);

    float inv = 1.f / (den + 1e-16f);
    float y[8];
#pragma unroll
    for (int k = 0; k < 8; ++k) y[k] = a[k] * inv;

    // head-mean over hd (t bits 2..3)
#pragma unroll
    for (int k = 0; k < 8; ++k) {
        y[k] += __shfl_xor(y[k], 4);
        y[k] += __shfl_xor(y[k], 8);
        y[k] *= 0.25f;
    }
    if (lane < 4) {
        int u = lane;
        uint4 bp = *(const uint4*)((const unsigned short*)bvec + u * 8);
        float v0 = y[0] + bflo(bp.x), v1 = y[1] + bfhi(bp.x);
        float v2 = y[2] + bflo(bp.y), v3 = y[3] + bfhi(bp.y);
        float v4 = y[4] + bflo(bp.z), v5 = y[5] + bfhi(bp.z);
        float v6 = y[6] + bflo(bp.w), v7 = y[7] + bfhi(bp.w);
        if (flag[0]) {
            float4* op = (float4*)outv + (size_t)n * 8 + u * 2;
            op[0] = make_float4(v0, v1, v2, v3);
            op[1] = make_float4(v4, v5, v6, v7);
        } else {
            uint4 pk;
            pk.x = packbf(v0, v1); pk.y = packbf(v2, v3);
            pk.z = packbf(v4, v5); pk.w = packbf(v6, v7);
            ((uint4*)outv)[(size_t)n * 4 + u] = pk;
        }
    }
}

extern "C" void kernel_launch(void* const* d_in, const int* in_sizes, int n_in,
                              void* d_out, int out_size, void* d_ws, size_t ws_size,
                              hipStream_t stream) {
    const void* x  = d_in[0];
    const int*  ei = (const int*)d_in[1];

    int N = in_sizes[0] / 128;
    int E = in_sizes[1] / 2;
    const int* srcI = ei;
    const int* dstI = ei + E;

    int NB = (N + 127) >> 7;
    int CAP = (E / NB + 1024 + 511) & ~511;

    char* w = (char*)d_ws;
    size_t o = 0;
    auto carve = [&](size_t bytes) {
        void* p = w + o;
        o += (bytes + 255) & ~(size_t)255;
        return p;
    };
    int*  dtFlag = (int*)carve(256);
    bf16* WTall = (bf16*)carve(4 * 16384 * 2);
    bf16* sv   = (bf16*)carve(14 * 128 * 2);
    bf16* vaT  = (bf16*)carve(3 * 16 * 128 * 2);
    bf16* bufP = (bf16*)carve((size_t)N * 128 * 2);  // h1, then h3
    bf16* bufQ = (bf16*)carve((size_t)N * 128 * 2);  // skip, then h2
    float* asA = (float*)carve((size_t)N * 4 * 4);
    float* adA = (float*)carve((size_t)N * 4 * 4);
    float* asB = (float*)carve((size_t)N * 4 * 4);
    float* adB = (float*)carve((size_t)N * 4 * 4);
    int* rowSE = (int*)carve((size_t)N * 2 * 4);
    int* colSrc= (int*)carve((size_t)NB * CAP * 4 + 64);
    int* ebuf  = (int*)carve((size_t)NB * CAP * 4);
    int* bucketCur = (int*)carve(512 * 4);

    detect_k<<<1, 64, 0, stream>>>(x, dtFlag, bucketCur, CAP);

    Ptr4 wp;
    wp.p[0] = d_in[2];  wp.p[1] = d_in[18];
    wp.p[2] = d_in[8];  wp.p[3] = d_in[14];
    Ptr14 ptrs;
    ptrs.p[0] = d_in[3];  ptrs.p[1] = d_in[4];  ptrs.p[2] = d_in[5];
    ptrs.p[3] = d_in[6];  ptrs.p[4] = d_in[7];
    ptrs.p[5] = d_in[9];  ptrs.p[6] = d_in[10]; ptrs.p[7] = d_in[11];
    ptrs.p[8] = d_in[12]; ptrs.p[9] = d_in[13];
    ptrs.p[10] = d_in[15]; ptrs.p[11] = d_in[16]; ptrs.p[12] = d_in[17];
    ptrs.p[13] = d_in[19];
    Ptr3 wv3;
    wv3.p[0] = d_in[2]; wv3.p[1] = d_in[8]; wv3.p[2] = d_in[14];
    Ptr6 av6;
    av6.p[0] = d_in[3];  av6.p[1] = d_in[4];
    av6.p[2] = d_in[9];  av6.p[3] = d_in[10];
    av6.p[4] = d_in[15]; av6.p[5] = d_in[16];

    stage_k<<<281, 256, 0, stream>>>(wp, WTall, ptrs, sv, wv3, av6, vaT, dtFlag);

    bscatter_k<<<(E + SCAT_EPB - 1) / SCAT_EPB, 256, 0, stream>>>(srcI, dstI,
                                                                 bucketCur, ebuf, E, NB, CAP);
    build_k<<<NB, 256, 0, stream>>>(ebuf, bucketCur, rowSE, colSrc, N, CAP);

    int gb = (N + 63) / 64;
    int nbF = (N + 15) / 16;
    int nb4 = (N + 3) / 4;

    // layer 1 gemm: h1 -> bufP, skip -> bufQ, alpha1 -> asA/adA
    gemm_k<1><<<gb, 256, 0, stream>>>(x, WTall, bufP, bufQ, sv + 13 * 128,
                                      vaT, asA, adA, N, dtFlag);
    // agg1 + gemm2 fused: gather bufP, skip/h2 in bufQ, alpha2 -> asB/adB
    aggemm_k<1><<<nbF, 256, 0, stream>>>(bufP, asA, adA, rowSE, colSrc,
                                         sv + 2 * 128, sv + 3 * 128, sv + 4 * 128,
                                         WTall + 2 * 16384, vaT + 2048,
                                         bufQ, asB, adB, N);
    // agg2 + gemm3 fused: gather bufQ, h3 -> bufP, alpha3 -> asA/adA
    aggemm_k<2><<<nbF, 256, 0, stream>>>(bufQ, asB, adB, rowSE, colSrc,
                                         sv + 7 * 128, sv + 8 * 128, sv + 9 * 128,
                                         WTall + 3 * 16384, vaT + 4096,
                                         bufP, asA, adA, N);
    // layer 3 agg: gather bufP -> d_out
    agg3_k<<<nb4, 256, 0, stream>>>(bufP, asA, adA, rowSE, colSrc,
                                    sv + 12 * 128, d_out, N, dtFlag);
}